// Round 8
// baseline (312.775 us; speedup 1.0000x reference)
//
#include <hip/hip_runtime.h>
#include <hip/hip_bf16.h>
#include <math.h>

#define BB 2
#define SS 2048
#define EE 2048
#define NQ 16
#define NKV 4
#define HD 128
#define WINDOW 512

typedef __hip_bfloat16 bf16;
typedef short short8 __attribute__((ext_vector_type(8)));   // 8 bf16 (4 VGPRs)
typedef float f32x4 __attribute__((ext_vector_type(4)));

__device__ __forceinline__ float toF(bf16 v) { return __bfloat162float(v); }
__device__ __forceinline__ bf16 toB(float v) { return __float2bfloat16(v); }

// async global->LDS, 16B per lane. LDS dest = wave-uniform base + lane*16.
__device__ __forceinline__ void gld_lds16(const void* g, void* l) {
    __builtin_amdgcn_global_load_lds(
        (const __attribute__((address_space(1))) void*)g,
        (__attribute__((address_space(3))) void*)l, 16, 0, 0);
}

template <int V> __device__ __forceinline__ void waitvm() {
    if constexpr (V == 6)      asm volatile("s_waitcnt vmcnt(6)" ::: "memory");
    else if constexpr (V == 4) asm volatile("s_waitcnt vmcnt(4)" ::: "memory");
    else if constexpr (V == 3) asm volatile("s_waitcnt vmcnt(3)" ::: "memory");
    else                       asm volatile("s_waitcnt vmcnt(0)" ::: "memory");
}

// ---------------------------------------------------------------------------
// fp32 -> bf16 elementwise (n % 4 == 0)
// ---------------------------------------------------------------------------
__global__ __launch_bounds__(256) void convert_bf16(const float* __restrict__ in,
                                                    bf16* __restrict__ out, int n) {
    int i = (blockIdx.x * 256 + threadIdx.x) * 4;
    if (i >= n) return;
    const float4 v = *(const float4*)(in + i);
    bf16 o[4] = {toB(v.x), toB(v.y), toB(v.z), toB(v.w)};
    *(uint2*)(out + i) = *(const uint2*)o;
}

// ---------------------------------------------------------------------------
// fp32 [K][N] -> bf16 [N][K] transpose. Generic (Wo).
// ---------------------------------------------------------------------------
__global__ __launch_bounds__(256) void convert_transpose(const float* __restrict__ in,
                                                         bf16* __restrict__ out,
                                                         int K, int N) {
    __shared__ float tile[32][33];
    const int t = threadIdx.x;
    const int tx = t & 31, ty = t >> 5;   // 32 x 8
    const int n0 = blockIdx.x * 32, k0 = blockIdx.y * 32;
#pragma unroll
    for (int r = 0; r < 4; r++)
        tile[ty + r * 8][tx] = in[(size_t)(k0 + ty + r * 8) * N + n0 + tx];
    __syncthreads();
#pragma unroll
    for (int r = 0; r < 4; r++)
        out[(size_t)(n0 + ty + r * 8) * K + k0 + tx] = toB(tile[tx][ty + r * 8]);
}

// ---------------------------------------------------------------------------
// Fused Wq/Wk/Wv transpose into packed [3072][2048] bf16.
// ---------------------------------------------------------------------------
__global__ __launch_bounds__(256) void convert_transpose_qkv(
    const float* __restrict__ Wq, const float* __restrict__ Wk,
    const float* __restrict__ Wv, bf16* __restrict__ out) {
    __shared__ float tile[32][33];
    const int t = threadIdx.x;
    const int tx = t & 31, ty = t >> 5;
    const int n0 = blockIdx.x * 32, k0 = blockIdx.y * 32;
    const float* src; int N, nl0;
    if (n0 < 2048)      { src = Wq; N = 2048; nl0 = n0; }
    else if (n0 < 2560) { src = Wk; N = 512;  nl0 = n0 - 2048; }
    else                { src = Wv; N = 512;  nl0 = n0 - 2560; }
#pragma unroll
    for (int r = 0; r < 4; r++)
        tile[ty + r * 8][tx] = src[(size_t)(k0 + ty + r * 8) * N + nl0 + tx];
    __syncthreads();
#pragma unroll
    for (int r = 0; r < 4; r++)
        out[(size_t)(n0 + ty + r * 8) * 2048 + k0 + tx] = toB(tile[tx][ty + r * 8]);
}

// ---------------------------------------------------------------------------
// MFMA GEMM v8: faithful 8-phase k-half template (m201 structure).
// BM=256, BK=64 (2 k-halves of 32), 512 thr = 8 waves (2M x 4N),
// per-wave output 128 x BN/4. 16x16x32 MFMA (16-row frag reads = the
// measured-0-conflict LDS geometry). LDS [buf][kh][rows*32], XOR swizzle:
// 16B slot s of row r holds k-group s^((r>>1)&3); reads slot lq^((row>>1)&3).
//
// Per K-tile t (buf cb = t&1), 4 phases, staging tile t+1 into cb^1:
//   p0: read B(kh0)+A(i0-3,kh0); stage A-kh0(t+1); BAR; 4xNJ MFMA; BAR
//   p1: read A(i4-7,kh0);        stage B-kh0(t+1); BAR; MFMA; vmcnt(KEEP); BAR
//   p2: read B(kh1)+A(i0-3,kh1); stage A-kh1(t+1); BAR; MFMA; BAR
//   p3: read A(i4-7,kh1);        stage B-kh1(t+1); BAR; MFMA; vmcnt(KEEP); BAR
// KEEP = LA+LB = loads of the 2 NEWEST halves; the counted wait retires
// exactly the 2 oldest halves (staged 3-4 phases earlier) - never a drain.
// RAW: every wave's vmcnt precedes the barrier preceding the reads of the
// guarded halves -> whole half landed before any wave reads it.
// WAR: a half is overwritten >=2 barriers after its last readers' MFMAs
// consumed it (reads are consumed within their own phase, pre-barrier).
// Tail (t=NT-1, no stages): the phase-1 wait becomes vmcnt(0).
// MODE 0: fp32 out + bias (BN=128, NJ=2). MODE 1: per-16-col QKV routing,
// RoPE fused Q/K, V stored transposed [b][hkv][d][s] (BN=256, NJ=4).
// XCD slab mapping: lin%8 -> XCD owns gy/8 contiguous m-rows, n-major.
// ---------------------------------------------------------------------------
template <int MODE, int BN>
__global__ __launch_bounds__(512, 2) void mfma_gemm_v8(
    const bf16* __restrict__ A, const bf16* __restrict__ BT,
    const float* __restrict__ b0, const float* __restrict__ b1,
    const float* __restrict__ b2,
    float* __restrict__ Yf,
    bf16* __restrict__ Yq, bf16* __restrict__ Yk, bf16* __restrict__ Yv,
    int M, int N, int K) {
    constexpr int NI = 8;                  // per-wave row frags (128/16)
    constexpr int NJ = BN / 64;            // per-wave col frags (4 or 2)
    constexpr int LA = 2;                  // A-half: 16KB -> 2 gld/thread
    constexpr int LB = BN / 128;           // B-half gld/thread (2 or 1)
    constexpr int KEEP = LA + LB;

    __shared__ __align__(16) bf16 As[2][2][256 * 32];   // 64 KB
    __shared__ __align__(16) bf16 Bs[2][2][BN * 32];    // 64/32 KB

    const int tid = threadIdx.x;
    const int lane = tid & 63;
    const int w = tid >> 6;                // 0..7
    const int wm = w >> 2;                 // 0..1
    const int wn = w & 3;                  // 0..3

    // ---- XCD-slab tile mapping (bijective; gy % 8 == 0) ----
    const int gx = gridDim.x, gy = gridDim.y;
    const int lin = blockIdx.y * gx + blockIdx.x;
    const int xcd = lin & 7;
    const int idx = lin >> 3;
    const int rpx = gy >> 3;
    const int tn = idx / rpx;
    const int tm = xcd * rpx + (idx % rpx);
    const int m0 = tm * 256, n0 = tn * BN;

    const int lr = lane & 15;
    const int lq = lane >> 4;
    const int NT = K >> 6;                 // 32 for K=2048

    // ---- staging: one k-half (rows x 32 cols) per call ----
    auto stA = [&](int b, int kh, int t) {
#pragma unroll
        for (int l = 0; l < LA; l++) {
            const int g16 = w * LA + l;                // 16-row group
            const int row = g16 * 16 + (lane >> 2);
            const int kg = (lane & 3) ^ ((row >> 1) & 3);
            gld_lds16(A + (size_t)(m0 + row) * K + t * 64 + kh * 32 + kg * 8,
                      &As[b][kh][g16 * 512]);
        }
    };
    auto stB = [&](int b, int kh, int t) {
#pragma unroll
        for (int l = 0; l < LB; l++) {
            const int g16 = w * LB + l;
            const int row = g16 * 16 + (lane >> 2);
            const int kg = (lane & 3) ^ ((row >> 1) & 3);
            gld_lds16(BT + (size_t)(n0 + row) * K + t * 64 + kh * 32 + kg * 8,
                      &Bs[b][kh][g16 * 512]);
        }
    };

    // ---- fragment reads ----
    auto rdA = [&](int b, int kh, int i0, short8 (&af)[4]) {
#pragma unroll
        for (int i2 = 0; i2 < 4; i2++) {
            const int row = wm * 128 + (i0 + i2) * 16 + lr;
            const int sl = lq ^ ((row >> 1) & 3);
            af[i2] = *(const short8*)(&As[b][kh][row * 32 + sl * 8]);
        }
    };
    auto rdB = [&](int b, int kh, short8 (&bf)[NJ]) {
#pragma unroll
        for (int j = 0; j < NJ; j++) {
            const int row = wn * (NJ * 16) + j * 16 + lr;
            const int sl = lq ^ ((row >> 1) & 3);
            bf[j] = *(const short8*)(&Bs[b][kh][row * 32 + sl * 8]);
        }
    };

    f32x4 acc[NI][NJ];
#pragma unroll
    for (int i = 0; i < NI; i++)
#pragma unroll
        for (int j = 0; j < NJ; j++) acc[i][j] = (f32x4)0.f;

    auto cl = [&](int i0, short8 (&af)[4], short8 (&bf)[NJ]) {
        __builtin_amdgcn_s_setprio(1);
#pragma unroll
        for (int i2 = 0; i2 < 4; i2++)
#pragma unroll
            for (int j = 0; j < NJ; j++)
                acc[i0 + i2][j] = __builtin_amdgcn_mfma_f32_16x16x32_bf16(
                    af[i2], bf[j], acc[i0 + i2][j], 0, 0, 0);
        __builtin_amdgcn_s_setprio(0);
    };

    // prologue: all 4 halves of tile 0 -> buf 0; drain; publish.
    stA(0, 0, 0); stB(0, 0, 0); stA(0, 1, 0); stB(0, 1, 0);
    waitvm<0>();
    __builtin_amdgcn_s_barrier();

    short8 afr[4], bfr[NJ];
    for (int t = 0; t < NT; ++t) {
        const int cb = t & 1;
        const bool st = (t + 1 < NT);
        // ---- phase 0: kh0, i 0-3 ----
        rdB(cb, 0, bfr);
        rdA(cb, 0, 0, afr);
        if (st) stA(cb ^ 1, 0, t + 1);
        __builtin_amdgcn_s_barrier();
        cl(0, afr, bfr);
        __builtin_amdgcn_s_barrier();
        // ---- phase 1: kh0, i 4-7 ----
        rdA(cb, 0, 4, afr);
        if (st) stB(cb ^ 1, 0, t + 1);
        __builtin_amdgcn_s_barrier();
        cl(4, afr, bfr);
        if (st) waitvm<KEEP>(); else waitvm<0>();
        __builtin_amdgcn_sched_barrier(0);
        __builtin_amdgcn_s_barrier();
        // ---- phase 2: kh1, i 0-3 ----
        rdB(cb, 1, bfr);
        rdA(cb, 1, 0, afr);
        if (st) stA(cb ^ 1, 1, t + 1);
        __builtin_amdgcn_s_barrier();
        cl(0, afr, bfr);
        __builtin_amdgcn_s_barrier();
        // ---- phase 3: kh1, i 4-7 ----
        rdA(cb, 1, 4, afr);
        if (st) stB(cb ^ 1, 1, t + 1);
        __builtin_amdgcn_s_barrier();
        cl(4, afr, bfr);
        if (st) waitvm<KEEP>(); else waitvm<0>();
        __builtin_amdgcn_sched_barrier(0);
        __builtin_amdgcn_s_barrier();
    }

    if (MODE == 0) {
#pragma unroll
        for (int j = 0; j < NJ; j++) {
            const int col = n0 + wn * (NJ * 16) + j * 16 + lr;
            const float bj = b0[col];
#pragma unroll
            for (int i = 0; i < NI; i++) {
                const int row = m0 + wm * 128 + i * 16 + lq * 4;
#pragma unroll
                for (int r = 0; r < 4; r++)
                    Yf[(size_t)(row + r) * N + col] = acc[i][j][r] + bj;
            }
        }
    } else {
        // per-16-col-fragment routing (boundaries 2048/2560 are 16-aligned)
#pragma unroll
        for (int j = 0; j < NJ; j++) {
            const int gcol = n0 + wn * (NJ * 16) + j * 16 + lr;
            if (gcol < 2560) {
                bf16* outp; const float* bias; int ldc, col;
                if (gcol < 2048) { outp = Yq; bias = b0; ldc = 2048; col = gcol; }
                else             { outp = Yk; bias = b1; ldc = 512;  col = gcol - 2048; }
                const float bj = bias[col];
                const int d2 = (col & 127) >> 1;
                const bool odd = col & 1;
                const float freq = __expf(-0.14384103622589045f * (float)d2); // ln(1e4)*2/128
#pragma unroll
                for (int i = 0; i < NI; i++) {
                    const int row = m0 + wm * 128 + i * 16 + lq * 4;
#pragma unroll
                    for (int r = 0; r < 4; r++) {
                        const float v = acc[i][j][r] + bj;
                        const float p = __shfl_xor(v, 1, 64);
                        const float ang = (float)((row + r) & (SS - 1)) * freq;
                        float sn, cs;
                        __sincosf(ang, &sn, &cs);
                        const float o = odd ? (p * sn + v * cs) : (v * cs - p * sn);
                        outp[(size_t)(row + r) * ldc + col] = toB(o);
                    }
                }
            } else {
                // V: store transposed [b][hkv][d][s]; 4 acc rows = 4 consecutive s.
                const int col = gcol - 2560;       // 0..511
                const float bj = b2[col];
                const int hkv = col >> 7, d = col & 127;
#pragma unroll
                for (int i = 0; i < NI; i++) {
                    const int row = m0 + wm * 128 + i * 16 + lq * 4;
                    const int bb = row >> 11, sr = row & (SS - 1);
                    union { bf16 b[4]; uint2 u; } o4;
#pragma unroll
                    for (int r = 0; r < 4; r++) o4.b[r] = toB(acc[i][j][r] + bj);
                    *(uint2*)(Yv + (((size_t)bb * NKV + hkv) * HD + d) * SS + sr) = o4.u;
                }
            }
        }
    }
}

// ---------------------------------------------------------------------------
// MFMA flash attention, windowed causal, GQA (r7: K/V double-buffered).
// ---------------------------------------------------------------------------
__global__ __launch_bounds__(256) void attn_mfma(const bf16* __restrict__ Q,
                                                 const bf16* __restrict__ K,
                                                 const bf16* __restrict__ VT,
                                                 bf16* __restrict__ Oout) {
    __shared__ bf16 Ks[2][64 * 128];   // [key][d], slot-swizzled
    __shared__ bf16 Vs[2][128 * 64];   // [d][key] (V^T), slot-swizzled
    __shared__ bf16 Ps[4 * 16 * 72];   // per-wave P tile, pad 72

    const int t = threadIdx.x;
    const int lane = t & 63;
    const int w = t >> 6;
    const int q0 = blockIdx.x * 64;
    const int h = blockIdx.y;
    const int b = blockIdx.z;
    const int hkv = h >> 2;
    const int lr = lane & 15;
    const int lq = lane >> 4;
    const float scale = 0.08838834764831845f;  // 1/sqrt(128)

    short8 aq[4];
    {
        const int q = q0 + w * 16 + lr;
        const bf16* qp = Q + (((size_t)b * SS + q) * NQ + h) * HD + lq * 8;
#pragma unroll
        for (int ks = 0; ks < 4; ks++) aq[ks] = *(const short8*)(qp + ks * 32);
    }

    const int krow = w * 16 + (lane >> 4);
    const int vrow = w * 32 + (lane >> 3);
    const bf16* Kbase = K + ((size_t)b * SS * NKV + hkv) * HD;
    const bf16* Vbase = VT + (((size_t)b * NKV + hkv) * HD) * SS;

    auto stageKV = [&](int c0s, int bufi) {
        bf16* Kd = &Ks[bufi][0];
        bf16* Vd = &Vs[bufi][0];
#pragma unroll
        for (int s = 0; s < 4; s++) {
            const int r_ = krow + s * 4;
            const int g_ = (lane & 15) ^ (r_ & 7);
            gld_lds16(Kbase + (size_t)(c0s + r_) * (NKV * HD) + g_ * 8,
                      Kd + (w * 16 + s * 4) * 128);
        }
#pragma unroll
        for (int s = 0; s < 4; s++) {
            const int d_ = vrow + s * 8;
            const int g_ = (lane & 7) ^ (d_ & 7);
            gld_lds16(Vbase + (size_t)d_ * SS + c0s + g_ * 8,
                      Vd + (w * 32 + s * 8) * 64);
        }
    };

    f32x4 Oa[8];
#pragma unroll
    for (int nb = 0; nb < 8; nb++) Oa[nb] = (f32x4)0.f;
    float mprev[4] = {-3.0e38f, -3.0e38f, -3.0e38f, -3.0e38f};
    float lsum[4] = {0.f, 0.f, 0.f, 0.f};

    bf16* Pw = Ps + w * 16 * 72;
    const int jstart = (q0 >= WINDOW) ? (q0 - WINDOW) : 0;

    stageKV(jstart, 0);
    asm volatile("s_waitcnt vmcnt(0)" ::: "memory");
    __syncthreads();

    int cb = 0;
    for (int c0 = jstart; c0 <= q0; c0 += 64) {
        if (c0 + 64 <= q0) stageKV(c0 + 64, cb ^ 1);   // hidden under compute
        const bf16* Ksb = &Ks[cb][0];
        const bf16* Vsb = &Vs[cb][0];

        f32x4 sa[4];
#pragma unroll
        for (int nb = 0; nb < 4; nb++) sa[nb] = (f32x4)0.f;
#pragma unroll
        for (int ks = 0; ks < 4; ks++) {
#pragma unroll
            for (int nb = 0; nb < 4; nb++) {
                const int slot = (ks * 4 + lq) ^ (lr & 7);
                short8 bk = *(const short8*)(Ksb + (nb * 16 + lr) * 128 + slot * 8);
                sa[nb] = __builtin_amdgcn_mfma_f32_16x16x32_bf16(aq[ks], bk, sa[nb], 0, 0, 0);
            }
        }

        const int rowb = q0 + w * 16 + lq * 4;
        const bool noMask = (c0 + 63 <= q0 + w * 16) &&
                            (q0 + w * 16 + 15 - c0 <= WINDOW);
        float pr[4][4], alpha[4];
#pragma unroll
        for (int r = 0; r < 4; r++) {
            const int row = rowb + r;
            float sv[4];
            float mx = -3.0e38f;
            if (noMask) {
#pragma unroll
                for (int nb = 0; nb < 4; nb++) {
                    const float s = sa[nb][r] * scale;
                    sv[nb] = s;
                    mx = fmaxf(mx, s);
                }
            } else {
#pragma unroll
                for (int nb = 0; nb < 4; nb++) {
                    const int col = c0 + nb * 16 + lr;
                    const bool valid = (col <= row) && (row - col <= WINDOW);
                    const float s = valid ? sa[nb][r] * scale : -3.0e38f;
                    sv[nb] = s;
                    mx = fmaxf(mx, s);
                }
            }
#pragma unroll
            for (int off = 1; off < 16; off <<= 1) mx = fmaxf(mx, __shfl_xor(mx, off, 64));
            const float mn = fmaxf(fmaxf(mprev[r], mx), -1.0e30f);
            alpha[r] = __expf(mprev[r] - mn);
            mprev[r] = mn;
            float rs = 0.f;
#pragma unroll
            for (int nb = 0; nb < 4; nb++) {
                const float p = __expf(sv[nb] - mn);
                pr[r][nb] = p;
                rs += p;
            }
#pragma unroll
            for (int off = 1; off < 16; off <<= 1) rs += __shfl_xor(rs, off, 64);
            lsum[r] = lsum[r] * alpha[r] + rs;
        }

#pragma unroll
        for (int r = 0; r < 4; r++)
#pragma unroll
            for (int nb = 0; nb < 4; nb++)
                Pw[(lq * 4 + r) * 72 + nb * 16 + lr] = toB(pr[r][nb]);

#pragma unroll
        for (int nb = 0; nb < 8; nb++)
#pragma unroll
            for (int r = 0; r < 4; r++) Oa[nb][r] *= alpha[r];
#pragma unroll
        for (int ks = 0; ks < 2; ks++) {
            short8 pa = *(const short8*)(Pw + lr * 72 + ks * 32 + lq * 8);
#pragma unroll
            for (int nb = 0; nb < 8; nb++) {
                const int slot = (ks * 4 + lq) ^ (lr & 7);
                short8 bv = *(const short8*)(Vsb + (nb * 16 + lr) * 64 + slot * 8);
                Oa[nb] = __builtin_amdgcn_mfma_f32_16x16x32_bf16(pa, bv, Oa[nb], 0, 0, 0);
            }
        }

        __syncthreads();   // drains vmcnt (stage already hidden) + WAR epoch
        cb ^= 1;
    }

    float linv[4];
#pragma unroll
    for (int r = 0; r < 4; r++) linv[r] = 1.f / lsum[r];
    const int rowb = q0 + w * 16 + lq * 4;
#pragma unroll
    for (int nb = 0; nb < 8; nb++)
#pragma unroll
        for (int r = 0; r < 4; r++)
            Oout[(((size_t)b * SS + rowb + r) * NQ + h) * HD + nb * 16 + lr] =
                toB(Oa[nb][r] * linv[r]);
}

// ---------------------------------------------------------------------------
extern "C" void kernel_launch(void* const* d_in, const int* in_sizes, int n_in,
                              void* d_out, int out_size, void* d_ws, size_t ws_size,
                              hipStream_t stream) {
    const float* x  = (const float*)d_in[0];
    const float* Wq = (const float*)d_in[1];
    const float* bq = (const float*)d_in[2];
    const float* Wk = (const float*)d_in[3];
    const float* bk = (const float*)d_in[4];
    const float* Wv = (const float*)d_in[5];
    const float* bv = (const float*)d_in[6];
    const float* Wo = (const float*)d_in[7];
    const float* bo = (const float*)d_in[8];
    float* out = (float*)d_out;

    const int M   = BB * SS;       // 4096
    const int DQ  = NQ * HD;       // 2048
    const int DKV = NKV * HD;      // 512
    const int NPK = DQ + 2 * DKV;  // 3072

    bf16* xb     = (bf16*)d_ws;                       // 4096*2048
    bf16* WqkvT  = xb + (size_t)M * EE;               // 3072*2048
    bf16* WoT    = WqkvT + (size_t)NPK * EE;          // 2048*2048
    bf16* Qb     = WoT + (size_t)EE * DQ;             // 4096*2048 (attn out in-place)
    bf16* Kb     = Qb + (size_t)M * DQ;               // 4096*512
    bf16* Vb     = Kb + (size_t)M * DKV;              // 4096*512  (V^T layout)

    convert_bf16<<<(M * EE / 4 + 255) / 256, 256, 0, stream>>>(x, xb, M * EE);
    convert_transpose_qkv<<<dim3(NPK / 32, EE / 32), 256, 0, stream>>>(Wq, Wk, Wv, WqkvT);
    convert_transpose<<<dim3(DQ / 32, DQ / 32), 256, 0, stream>>>(Wo, WoT, DQ, EE);

    // QKV projection + bias + RoPE; 256x256 8-phase template, grid 12x16
    mfma_gemm_v8<1, 256><<<dim3(NPK / 256, M / 256), 512, 0, stream>>>(
        xb, WqkvT, bq, bk, bv, nullptr, Qb, Kb, Vb, M, NPK, EE);

    attn_mfma<<<dim3(SS / 64, NQ, BB), 256, 0, stream>>>(Qb, Kb, Vb, Qb);

    // out projection; 256x128 8-phase template, grid 16x16 (full CU fill)
    mfma_gemm_v8<0, 128><<<dim3(EE / 128, M / 256), 512, 0, stream>>>(
        Qb, WoT, bo, nullptr, nullptr, out, nullptr, nullptr, nullptr, M, EE, DQ);
}